// Round 1
// baseline (5739.130 us; speedup 1.0000x reference)
//
#include <hip/hip_runtime.h>

#define NNODES 40000
#define NEDGES 640000
#define DIN 128
#define DHID 256
#define DOUT 47

// ---------------- degree ----------------
__global__ void deg_kernel(const int* __restrict__ dst, float* __restrict__ deg) {
    int t = blockIdx.x * blockDim.x + threadIdx.x;
    if (t < NEDGES) atomicAdd(&deg[dst[t]], 1.0f);
}

__global__ void invdeg_kernel(float* __restrict__ deg) {
    int t = blockIdx.x * blockDim.x + threadIdx.x;
    if (t < NNODES) {
        float d = deg[t];
        deg[t] = 1.0f / fmaxf(d, 1.0f);
    }
}

// ---------------- scatter-sum of h[src] into msum[dst] ----------------
// one thread = one float4 of one edge. shift = log2(d/4).
__global__ void scatter_kernel(const float* __restrict__ h,
                               const int* __restrict__ src,
                               const int* __restrict__ dst,
                               float* __restrict__ msum,
                               int shift) {
    int t = blockIdx.x * blockDim.x + threadIdx.x;
    int nWork = NEDGES << shift;
    if (t >= nWork) return;
    int e = t >> shift;
    int f = t & ((1 << shift) - 1);
    int d = 4 << shift;
    int s = src[e], dd = dst[e];
    const float4 v = ((const float4*)(h + (size_t)s * d))[f];
    float* p = msum + (size_t)dd * d + f * 4;
    atomicAdd(p + 0, v.x);
    atomicAdd(p + 1, v.y);
    atomicAdd(p + 2, v.z);
    atomicAdd(p + 3, v.w);
}

// ---------------- GEMM: out = relu?( [H | msum*invdeg] @ W + b ) ----------------
// A is the virtual concat [M, 2d]; W is [2d, N] row-major.
// 64x64 block tile, BK=16, 256 threads, 4x4 per thread. M=40000 (=625*64 exact).
template <bool RELU>
__global__ void gemm_cat_kernel(const float* __restrict__ H,
                                const float* __restrict__ Mn,
                                const float* __restrict__ invdeg,
                                const float* __restrict__ W,
                                const float* __restrict__ b,
                                float* __restrict__ out,
                                int d, int N) {
    __shared__ float As[16][64 + 1];  // [k][m]
    __shared__ float Bs[16][64];      // [k][n]

    const int tid = threadIdx.x;
    const int tx = tid & 15;         // 0..15 -> col group
    const int ty = tid >> 4;         // 0..15 -> row group
    const int rowBase = blockIdx.x * 64;
    const int col0 = blockIdx.y * 64;
    const int twoD = 2 * d;

    // A-load assignment: ar = m (0..63), ac*4 = k offset (0..12)
    const int ar = tid >> 2;
    const int ac = (tid & 3) * 4;
    // B-load assignment: br = k (0..15), bc = n offset
    const int br = tid >> 4;
    const int bc = (tid & 15) * 4;

    const int arow = rowBase + ar;
    const float inv = invdeg[arow];

    float acc[4][4];
#pragma unroll
    for (int i = 0; i < 4; ++i)
#pragma unroll
        for (int j = 0; j < 4; ++j) acc[i][j] = 0.0f;

    for (int k0 = 0; k0 < twoD; k0 += 16) {
        // load A tile (each thread: 4 consecutive k for one row)
        {
            int kg = k0 + ac;
            float4 v;
            if (kg < d) {
                v = *(const float4*)(H + (size_t)arow * d + kg);
            } else {
                v = *(const float4*)(Mn + (size_t)arow * d + (kg - d));
                v.x *= inv; v.y *= inv; v.z *= inv; v.w *= inv;
            }
            As[ac + 0][ar] = v.x;
            As[ac + 1][ar] = v.y;
            As[ac + 2][ar] = v.z;
            As[ac + 3][ar] = v.w;
        }
        // load B tile (scalar, zero-pad past N)
        {
            int kg = k0 + br;
#pragma unroll
            for (int q = 0; q < 4; ++q) {
                int col = col0 + bc + q;
                Bs[br][bc + q] = (col < N) ? W[(size_t)kg * N + col] : 0.0f;
            }
        }
        __syncthreads();

#pragma unroll
        for (int kk = 0; kk < 16; ++kk) {
            float ra[4], rb[4];
#pragma unroll
            for (int i = 0; i < 4; ++i) ra[i] = As[kk][ty * 4 + i];
#pragma unroll
            for (int j = 0; j < 4; ++j) rb[j] = Bs[kk][tx * 4 + j];
#pragma unroll
            for (int i = 0; i < 4; ++i)
#pragma unroll
                for (int j = 0; j < 4; ++j) acc[i][j] += ra[i] * rb[j];
        }
        __syncthreads();
    }

#pragma unroll
    for (int i = 0; i < 4; ++i) {
        int row = rowBase + ty * 4 + i;
#pragma unroll
        for (int j = 0; j < 4; ++j) {
            int col = col0 + tx * 4 + j;
            if (col < N) {
                float v = acc[i][j] + b[col];
                if (RELU) v = fmaxf(v, 0.0f);
                out[(size_t)row * N + col] = v;
            }
        }
    }
}

extern "C" void kernel_launch(void* const* d_in, const int* in_sizes, int n_in,
                              void* d_out, int out_size, void* d_ws, size_t ws_size,
                              hipStream_t stream) {
    const float* x  = (const float*)d_in[0];
    const float* W1 = (const float*)d_in[1];
    const float* b1 = (const float*)d_in[2];
    const float* W2 = (const float*)d_in[3];
    const float* b2 = (const float*)d_in[4];
    const float* W3 = (const float*)d_in[5];
    const float* b3 = (const float*)d_in[6];
    const int* src  = (const int*)d_in[7];
    const int* dst  = (const int*)d_in[8];
    float* out = (float*)d_out;

    // workspace layout
    float* deg  = (float*)d_ws;                       // 40960 (padded)
    float* buf0 = deg + 40960;                        // h1: 40000*256
    float* buf1 = buf0 + (size_t)NNODES * DHID;       // h2: 40000*256
    float* msum = buf1 + (size_t)NNODES * DHID;       // 40000*256

    // degree (shared across layers)
    hipMemsetAsync(deg, 0, NNODES * sizeof(float), stream);
    deg_kernel<<<(NEDGES + 255) / 256, 256, 0, stream>>>(dst, deg);
    invdeg_kernel<<<(NNODES + 255) / 256, 256, 0, stream>>>(deg);

    // ---- layer 1: d=128 -> 256, relu
    hipMemsetAsync(msum, 0, (size_t)NNODES * DIN * sizeof(float), stream);
    {
        int shift = 5;  // 128/4 = 32
        int nWork = NEDGES << shift;
        scatter_kernel<<<(nWork + 255) / 256, 256, 0, stream>>>(x, src, dst, msum, shift);
    }
    {
        dim3 grid(NNODES / 64, (DHID + 63) / 64);
        gemm_cat_kernel<true><<<grid, 256, 0, stream>>>(x, msum, deg, W1, b1, buf0, DIN, DHID);
    }

    // ---- layer 2: d=256 -> 256, relu
    hipMemsetAsync(msum, 0, (size_t)NNODES * DHID * sizeof(float), stream);
    {
        int shift = 6;  // 256/4 = 64
        int nWork = NEDGES << shift;
        scatter_kernel<<<(nWork + 255) / 256, 256, 0, stream>>>(buf0, src, dst, msum, shift);
    }
    {
        dim3 grid(NNODES / 64, (DHID + 63) / 64);
        gemm_cat_kernel<true><<<grid, 256, 0, stream>>>(buf0, msum, deg, W2, b2, buf1, DHID, DHID);
    }

    // ---- layer 3: d=256 -> 47, no relu
    hipMemsetAsync(msum, 0, (size_t)NNODES * DHID * sizeof(float), stream);
    {
        int shift = 6;
        int nWork = NEDGES << shift;
        scatter_kernel<<<(nWork + 255) / 256, 256, 0, stream>>>(buf1, src, dst, msum, shift);
    }
    {
        dim3 grid(NNODES / 64, (DOUT + 63) / 64);
        gemm_cat_kernel<false><<<grid, 256, 0, stream>>>(buf1, msum, deg, W3, b3, out, DHID, DOUT);
    }
}

// Round 2
// 693.700 us; speedup vs baseline: 8.2732x; 8.2732x over previous
//
#include <hip/hip_runtime.h>

#define NNODES 40000
#define NEDGES 640000
#define DIN 128
#define DHID 256
#define DOUT 47

// ---------------- CSR build ----------------
__global__ void hist_kernel(const int* __restrict__ dst, int* __restrict__ cnt) {
    int t = blockIdx.x * blockDim.x + threadIdx.x;
    if (t < NEDGES) atomicAdd(&cnt[dst[t]], 1);
}

// single-block exclusive scan of cnt[0..NNODES) -> rowptr[0..NNODES]
__global__ void scan_kernel(const int* __restrict__ cnt, int* __restrict__ rowptr) {
    __shared__ int partial[1024];
    const int t = threadIdx.x;
    const int CH = 40;  // 1024*40 = 40960 >= 40001
    const int base = t * CH;
    int s = 0;
#pragma unroll
    for (int i = 0; i < CH; ++i) {
        int idx = base + i;
        if (idx < NNODES) s += cnt[idx];
    }
    partial[t] = s;
    __syncthreads();
    for (int off = 1; off < 1024; off <<= 1) {
        int add = (t >= off) ? partial[t - off] : 0;
        __syncthreads();
        partial[t] += add;
        __syncthreads();
    }
    int offset = (t == 0) ? 0 : partial[t - 1];
    s = 0;
#pragma unroll
    for (int i = 0; i < CH; ++i) {
        int idx = base + i;
        if (idx <= NNODES) rowptr[idx] = offset + s;
        if (idx < NNODES) s += cnt[idx];
    }
}

__global__ void fill_kernel(const int* __restrict__ src, const int* __restrict__ dst,
                            const int* __restrict__ rowptr, int* __restrict__ fill,
                            int* __restrict__ eidx) {
    int e = blockIdx.x * blockDim.x + threadIdx.x;
    if (e < NEDGES) {
        int d = dst[e];
        int pos = rowptr[d] + atomicAdd(&fill[d], 1);
        eidx[pos] = src[e];
    }
}

// ---------------- mean aggregation: one wave per node ----------------
template <int D>
__global__ void agg_kernel(const float* __restrict__ h,
                           const int* __restrict__ rowptr,
                           const int* __restrict__ eidx,
                           float* __restrict__ mean) {
    constexpr int VPL = D / 64;  // floats per lane (2 or 4)
    const int wpb = blockDim.x >> 6;
    const int node = blockIdx.x * wpb + (threadIdx.x >> 6);
    if (node >= NNODES) return;
    const int lane = threadIdx.x & 63;
    const int beg = rowptr[node], end = rowptr[node + 1];

    float acc[VPL];
#pragma unroll
    for (int i = 0; i < VPL; ++i) acc[i] = 0.0f;

    for (int base = beg; base < end; base += 64) {
        int n = min(64, end - base);
        int myidx = (base + lane < end) ? eidx[base + lane] : 0;
        for (int j = 0; j < n; ++j) {
            int s = __shfl(myidx, j);
            const float* row = h + (size_t)s * D;
            if constexpr (VPL == 4) {
                float4 v = *(const float4*)(row + lane * 4);
                acc[0] += v.x; acc[1] += v.y; acc[2] += v.z; acc[3] += v.w;
            } else {
                float2 v = *(const float2*)(row + lane * 2);
                acc[0] += v.x; acc[1] += v.y;
            }
        }
    }
    float inv = (end > beg) ? 1.0f / (float)(end - beg) : 0.0f;
    float* o = mean + (size_t)node * D;
    if constexpr (VPL == 4) {
        float4 r = make_float4(acc[0] * inv, acc[1] * inv, acc[2] * inv, acc[3] * inv);
        *(float4*)(o + lane * 4) = r;
    } else {
        float2 r = make_float2(acc[0] * inv, acc[1] * inv);
        *(float2*)(o + lane * 2) = r;
    }
}

// ---------------- GEMM: out = relu?( [H | Mean] @ W + b ) ----------------
// A is the virtual concat [M, 2d]; W is [2d, N] row-major.
// 64x64 block tile, BK=16, 256 threads, 4x4 per thread. M=40000 (=625*64 exact).
template <bool RELU>
__global__ void gemm_cat_kernel(const float* __restrict__ H,
                                const float* __restrict__ Mn,
                                const float* __restrict__ W,
                                const float* __restrict__ b,
                                float* __restrict__ out,
                                int d, int N) {
    __shared__ float As[16][64 + 1];  // [k][m]
    __shared__ float Bs[16][64];      // [k][n]

    const int tid = threadIdx.x;
    const int tx = tid & 15;
    const int ty = tid >> 4;
    const int rowBase = blockIdx.x * 64;
    const int col0 = blockIdx.y * 64;
    const int twoD = 2 * d;

    const int ar = tid >> 2;
    const int ac = (tid & 3) * 4;
    const int br = tid >> 4;
    const int bc = (tid & 15) * 4;

    const int arow = rowBase + ar;

    float acc[4][4];
#pragma unroll
    for (int i = 0; i < 4; ++i)
#pragma unroll
        for (int j = 0; j < 4; ++j) acc[i][j] = 0.0f;

    for (int k0 = 0; k0 < twoD; k0 += 16) {
        {
            int kg = k0 + ac;
            float4 v;
            if (kg < d) {
                v = *(const float4*)(H + (size_t)arow * d + kg);
            } else {
                v = *(const float4*)(Mn + (size_t)arow * d + (kg - d));
            }
            As[ac + 0][ar] = v.x;
            As[ac + 1][ar] = v.y;
            As[ac + 2][ar] = v.z;
            As[ac + 3][ar] = v.w;
        }
        {
            int kg = k0 + br;
#pragma unroll
            for (int q = 0; q < 4; ++q) {
                int col = col0 + bc + q;
                Bs[br][bc + q] = (col < N) ? W[(size_t)kg * N + col] : 0.0f;
            }
        }
        __syncthreads();

#pragma unroll
        for (int kk = 0; kk < 16; ++kk) {
            float ra[4], rb[4];
#pragma unroll
            for (int i = 0; i < 4; ++i) ra[i] = As[kk][ty * 4 + i];
#pragma unroll
            for (int j = 0; j < 4; ++j) rb[j] = Bs[kk][tx * 4 + j];
#pragma unroll
            for (int i = 0; i < 4; ++i)
#pragma unroll
                for (int j = 0; j < 4; ++j) acc[i][j] += ra[i] * rb[j];
        }
        __syncthreads();
    }

#pragma unroll
    for (int i = 0; i < 4; ++i) {
        int row = rowBase + ty * 4 + i;
#pragma unroll
        for (int j = 0; j < 4; ++j) {
            int col = col0 + tx * 4 + j;
            if (col < N) {
                float v = acc[i][j] + b[col];
                if (RELU) v = fmaxf(v, 0.0f);
                out[(size_t)row * N + col] = v;
            }
        }
    }
}

extern "C" void kernel_launch(void* const* d_in, const int* in_sizes, int n_in,
                              void* d_out, int out_size, void* d_ws, size_t ws_size,
                              hipStream_t stream) {
    const float* x  = (const float*)d_in[0];
    const float* W1 = (const float*)d_in[1];
    const float* b1 = (const float*)d_in[2];
    const float* W2 = (const float*)d_in[3];
    const float* b2 = (const float*)d_in[4];
    const float* W3 = (const float*)d_in[5];
    const float* b3 = (const float*)d_in[6];
    const int* src  = (const int*)d_in[7];
    const int* dst  = (const int*)d_in[8];
    float* out = (float*)d_out;

    // workspace layout
    int* rowptr = (int*)d_ws;                              // 40960 ints (40001 used)
    int* eidx   = rowptr + 40960;                          // 640000 ints
    float* buf0 = (float*)d_ws + 680960;                   // 40000*256 f32
    float* buf1 = buf0 + (size_t)NNODES * DHID;            // 40000*256 f32
    float* mean = buf1 + (size_t)NNODES * DHID;            // 40000*256 f32
    // cnt / fill alias the mean buffer during CSR build (mean written only after)
    int* cnt  = (int*)mean;
    int* fill = cnt + 40960;

    // ---- CSR build (once per call; deterministic up to in-node edge order,
    // which is irrelevant to the commutative mean) ----
    hipMemsetAsync(cnt, 0, 2 * 40960 * sizeof(int), stream);  // cnt + fill
    hist_kernel<<<(NEDGES + 255) / 256, 256, 0, stream>>>(dst, cnt);
    scan_kernel<<<1, 1024, 0, stream>>>(cnt, rowptr);
    fill_kernel<<<(NEDGES + 255) / 256, 256, 0, stream>>>(src, dst, rowptr, fill, eidx);

    // ---- layer 1: d=128 -> 256, relu
    agg_kernel<DIN><<<NNODES / 4, 256, 0, stream>>>(x, rowptr, eidx, mean);
    {
        dim3 grid(NNODES / 64, (DHID + 63) / 64);
        gemm_cat_kernel<true><<<grid, 256, 0, stream>>>(x, mean, W1, b1, buf0, DIN, DHID);
    }

    // ---- layer 2: d=256 -> 256, relu
    agg_kernel<DHID><<<NNODES / 4, 256, 0, stream>>>(buf0, rowptr, eidx, mean);
    {
        dim3 grid(NNODES / 64, (DHID + 63) / 64);
        gemm_cat_kernel<true><<<grid, 256, 0, stream>>>(buf0, mean, W2, b2, buf1, DHID, DHID);
    }

    // ---- layer 3: d=256 -> 47, no relu
    agg_kernel<DHID><<<NNODES / 4, 256, 0, stream>>>(buf1, rowptr, eidx, mean);
    {
        dim3 grid(NNODES / 64, (DOUT + 63) / 64);
        gemm_cat_kernel<false><<<grid, 256, 0, stream>>>(buf1, mean, W3, b3, out, DHID, DOUT);
    }
}

// Round 3
// 367.662 us; speedup vs baseline: 15.6098x; 1.8868x over previous
//
#include <hip/hip_runtime.h>

#define NNODES 40000
#define NEDGES 640000
#define DIN 128
#define DHID 256
#define DOUT 47

typedef __attribute__((ext_vector_type(8))) short short8;
typedef __attribute__((ext_vector_type(4))) float f32x4;

__device__ inline float bf2f(unsigned short u) {
    union { unsigned int i; float f; } c; c.i = ((unsigned int)u) << 16; return c.f;
}
__device__ inline unsigned short f2bf(float f) {
    union { float f; unsigned int i; } c; c.f = f;
    unsigned int x = c.i;
    x += 0x7fff + ((x >> 16) & 1);  // RNE
    return (unsigned short)(x >> 16);
}

// ---------------- CSR build ----------------
__global__ void hist_kernel(const int* __restrict__ dst, int* __restrict__ cnt) {
    int t = blockIdx.x * blockDim.x + threadIdx.x;
    if (t < NEDGES) atomicAdd(&cnt[dst[t]], 1);
}

__global__ void scan_kernel(const int* __restrict__ cnt, int* __restrict__ rowptr) {
    __shared__ int partial[1024];
    const int t = threadIdx.x;
    const int CH = 40;
    const int base = t * CH;
    int s = 0;
#pragma unroll
    for (int i = 0; i < CH; ++i) {
        int idx = base + i;
        if (idx < NNODES) s += cnt[idx];
    }
    partial[t] = s;
    __syncthreads();
    for (int off = 1; off < 1024; off <<= 1) {
        int add = (t >= off) ? partial[t - off] : 0;
        __syncthreads();
        partial[t] += add;
        __syncthreads();
    }
    int offset = (t == 0) ? 0 : partial[t - 1];
    s = 0;
#pragma unroll
    for (int i = 0; i < CH; ++i) {
        int idx = base + i;
        if (idx <= NNODES) rowptr[idx] = offset + s;
        if (idx < NNODES) s += cnt[idx];
    }
}

__global__ void fill_kernel(const int* __restrict__ src, const int* __restrict__ dst,
                            const int* __restrict__ rowptr, int* __restrict__ fill,
                            int* __restrict__ eidx) {
    int e = blockIdx.x * blockDim.x + threadIdx.x;
    if (e < NEDGES) {
        int d = dst[e];
        int pos = rowptr[d] + atomicAdd(&fill[d], 1);
        eidx[pos] = src[e];
    }
}

// ---------------- conversions ----------------
__global__ void f32_to_bf16_kernel(const float* __restrict__ in, unsigned short* __restrict__ out, int n) {
    int t = blockIdx.x * blockDim.x + threadIdx.x;
    if (t < n) out[t] = f2bf(in[t]);
}

// W [K][N] f32 -> Wt [N][K] bf16
__global__ void conv_wt_kernel(const float* __restrict__ W, unsigned short* __restrict__ Wt, int K, int N) {
    int t = blockIdx.x * blockDim.x + threadIdx.x;
    if (t < K * N) {
        int k = t / N, n = t - k * N;
        Wt[(size_t)n * K + k] = f2bf(W[t]);
    }
}

// ---------------- mean aggregation: one wave per node, bf16 in/out, f32 accum ----------------
template <int D>
__global__ void agg_bf16_kernel(const unsigned short* __restrict__ h,
                                const int* __restrict__ rowptr,
                                const int* __restrict__ eidx,
                                unsigned short* __restrict__ mean) {
    constexpr int VPL = D / 64;  // bf16 per lane: 2 (D=128) or 4 (D=256)
    const int node = blockIdx.x * (blockDim.x >> 6) + (threadIdx.x >> 6);
    if (node >= NNODES) return;
    const int lane = threadIdx.x & 63;
    const int beg = rowptr[node], end = rowptr[node + 1];

    float acc[VPL];
#pragma unroll
    for (int i = 0; i < VPL; ++i) acc[i] = 0.0f;

    for (int base = beg; base < end; base += 64) {
        int n = min(64, end - base);
        int myidx = (base + lane < end) ? eidx[base + lane] : 0;
        for (int j = 0; j < n; ++j) {
            int s = __shfl(myidx, j);
            const unsigned short* row = h + (size_t)s * D + lane * VPL;
            if constexpr (VPL == 4) {
                ushort4 v = *(const ushort4*)row;
                acc[0] += bf2f(v.x); acc[1] += bf2f(v.y);
                acc[2] += bf2f(v.z); acc[3] += bf2f(v.w);
            } else {
                ushort2 v = *(const ushort2*)row;
                acc[0] += bf2f(v.x); acc[1] += bf2f(v.y);
            }
        }
    }
    float inv = (end > beg) ? 1.0f / (float)(end - beg) : 0.0f;
    unsigned short* o = mean + (size_t)node * D + lane * VPL;
    if constexpr (VPL == 4) {
        ushort4 r;
        r.x = f2bf(acc[0] * inv); r.y = f2bf(acc[1] * inv);
        r.z = f2bf(acc[2] * inv); r.w = f2bf(acc[3] * inv);
        *(ushort4*)o = r;
    } else {
        ushort2 r;
        r.x = f2bf(acc[0] * inv); r.y = f2bf(acc[1] * inv);
        *(ushort2*)o = r;
    }
}

// ---------------- bf16 MFMA GEMM: out = act( [H | Mean] @ Wt^T + b ) ----------------
// A virtual concat [M, K=2d] bf16; Wt is [N][K] bf16. 128x128 tile, BK=32,
// 256 threads = 4 waves (2x2), each wave 64x64 via 4x4 mfma_f32_16x16x32_bf16.
template <bool RELU, bool F32OUT>
__launch_bounds__(256, 2)
__global__ void gemm_mfma_kernel(const unsigned short* __restrict__ H,
                                 const unsigned short* __restrict__ Mn,
                                 const unsigned short* __restrict__ Wt,
                                 const float* __restrict__ bias,
                                 void* __restrict__ outp,
                                 int d, int N) {
    const int K = 2 * d;
    __shared__ uint4 AsB[128 * 4];  // [row][slot] 16B slots, slot XOR-swizzled
    __shared__ uint4 BsB[128 * 4];

    const int tid = threadIdx.x;
    const int lane = tid & 63;
    const int wid = tid >> 6;
    const int wr = wid >> 1, wc = wid & 1;
    const int row0 = blockIdx.x * 128;
    const int col0 = blockIdx.y * 128;

    const int sr = tid >> 1;  // staging row 0..127
    const int sh = tid & 1;   // staging half (32B)
    const int gar = min(row0 + sr, NNODES - 1);
    const int gbr = min(col0 + sr, N - 1);
    const int ssw = (sr >> 1) & 3;

    f32x4 acc[4][4];
#pragma unroll
    for (int m = 0; m < 4; ++m)
#pragma unroll
        for (int n = 0; n < 4; ++n) {
            f32x4 z = {0.0f, 0.0f, 0.0f, 0.0f};
            acc[m][n] = z;
        }

    for (int k0 = 0; k0 < K; k0 += 32) {
        // stage A (virtual concat)
        {
            int kb = k0 + sh * 16;
            const unsigned short* p = (kb < d) ? (H + (size_t)gar * d + kb)
                                               : (Mn + (size_t)gar * d + (kb - d));
            uint4 v0 = *(const uint4*)p;
            uint4 v1 = *(const uint4*)(p + 8);
            AsB[sr * 4 + ((2 * sh) ^ ssw)]     = v0;
            AsB[sr * 4 + ((2 * sh + 1) ^ ssw)] = v1;
        }
        // stage B
        {
            const unsigned short* p = Wt + (size_t)gbr * K + k0 + sh * 16;
            uint4 v0 = *(const uint4*)p;
            uint4 v1 = *(const uint4*)(p + 8);
            BsB[sr * 4 + ((2 * sh) ^ ssw)]     = v0;
            BsB[sr * 4 + ((2 * sh + 1) ^ ssw)] = v1;
        }
        __syncthreads();

        short8 af[4], bfr[4];
        const int fr = lane & 15;
        const int slot = lane >> 4;
#pragma unroll
        for (int m = 0; m < 4; ++m) {
            int r = wr * 64 + m * 16 + fr;
            union { uint4 u; short8 s; } c;
            c.u = AsB[r * 4 + (slot ^ ((r >> 1) & 3))];
            af[m] = c.s;
        }
#pragma unroll
        for (int n = 0; n < 4; ++n) {
            int r = wc * 64 + n * 16 + fr;
            union { uint4 u; short8 s; } c;
            c.u = BsB[r * 4 + (slot ^ ((r >> 1) & 3))];
            bfr[n] = c.s;
        }
#pragma unroll
        for (int m = 0; m < 4; ++m)
#pragma unroll
            for (int n = 0; n < 4; ++n)
                acc[m][n] = __builtin_amdgcn_mfma_f32_16x16x32_bf16(af[m], bfr[n], acc[m][n], 0, 0, 0);
        __syncthreads();
    }

    // epilogue
#pragma unroll
    for (int m = 0; m < 4; ++m) {
#pragma unroll
        for (int n = 0; n < 4; ++n) {
            int col = col0 + wc * 64 + n * 16 + (lane & 15);
            if (col < N) {
                float bv = bias[col];
#pragma unroll
                for (int q = 0; q < 4; ++q) {
                    int row = row0 + wr * 64 + m * 16 + (lane >> 4) * 4 + q;
                    if (row < NNODES) {
                        float v = acc[m][n][q] + bv;
                        if (RELU) v = fmaxf(v, 0.0f);
                        if (F32OUT) ((float*)outp)[(size_t)row * N + col] = v;
                        else ((unsigned short*)outp)[(size_t)row * N + col] = f2bf(v);
                    }
                }
            }
        }
    }
}

extern "C" void kernel_launch(void* const* d_in, const int* in_sizes, int n_in,
                              void* d_out, int out_size, void* d_ws, size_t ws_size,
                              hipStream_t stream) {
    const float* x  = (const float*)d_in[0];
    const float* W1 = (const float*)d_in[1];
    const float* b1 = (const float*)d_in[2];
    const float* W2 = (const float*)d_in[3];
    const float* b2 = (const float*)d_in[4];
    const float* W3 = (const float*)d_in[5];
    const float* b3 = (const float*)d_in[6];
    const int* src  = (const int*)d_in[7];
    const int* dst  = (const int*)d_in[8];
    float* out = (float*)d_out;

    // workspace layout
    int* rowptr = (int*)d_ws;                 // 40960
    int* eidx   = rowptr + 40960;             // 640000
    int* cnt    = eidx + 640000;              // 40960
    int* fill   = cnt + 40960;                // 40960
    unsigned short* xbf  = (unsigned short*)(fill + 40960);  // 40000*128
    unsigned short* h1   = xbf + (size_t)NNODES * DIN;       // 40000*256
    unsigned short* h2   = h1 + (size_t)NNODES * DHID;       // 40000*256
    unsigned short* mean = h2 + (size_t)NNODES * DHID;       // 40000*256 (worst case)
    unsigned short* wt1  = mean + (size_t)NNODES * DHID;     // 256*256
    unsigned short* wt2  = wt1 + 2 * DIN * DHID;             // 256*512
    unsigned short* wt3  = wt2 + 2 * DHID * DHID;            // 47*512

    // ---- CSR build ----
    hipMemsetAsync(cnt, 0, 2 * 40960 * sizeof(int), stream);
    hist_kernel<<<(NEDGES + 255) / 256, 256, 0, stream>>>(dst, cnt);
    scan_kernel<<<1, 1024, 0, stream>>>(cnt, rowptr);
    fill_kernel<<<(NEDGES + 255) / 256, 256, 0, stream>>>(src, dst, rowptr, fill, eidx);

    // ---- conversions ----
    f32_to_bf16_kernel<<<(NNODES * DIN + 255) / 256, 256, 0, stream>>>(x, xbf, NNODES * DIN);
    conv_wt_kernel<<<(2 * DIN * DHID + 255) / 256, 256, 0, stream>>>(W1, wt1, 2 * DIN, DHID);
    conv_wt_kernel<<<(2 * DHID * DHID + 255) / 256, 256, 0, stream>>>(W2, wt2, 2 * DHID, DHID);
    conv_wt_kernel<<<(2 * DHID * DOUT + 255) / 256, 256, 0, stream>>>(W3, wt3, 2 * DHID, DOUT);

    const int MB = (NNODES + 127) / 128;  // 313

    // ---- layer 1: d=128 -> 256, relu
    agg_bf16_kernel<DIN><<<NNODES / 4, 256, 0, stream>>>(xbf, rowptr, eidx, mean);
    {
        dim3 grid(MB, 2);
        gemm_mfma_kernel<true, false><<<grid, 256, 0, stream>>>(xbf, mean, wt1, b1, h1, DIN, DHID);
    }

    // ---- layer 2: d=256 -> 256, relu
    agg_bf16_kernel<DHID><<<NNODES / 4, 256, 0, stream>>>(h1, rowptr, eidx, mean);
    {
        dim3 grid(MB, 2);
        gemm_mfma_kernel<true, false><<<grid, 256, 0, stream>>>(h1, mean, wt2, b2, h2, DHID, DHID);
    }

    // ---- layer 3: d=256 -> 47, no relu, f32 out
    agg_bf16_kernel<DHID><<<NNODES / 4, 256, 0, stream>>>(h2, rowptr, eidx, mean);
    {
        dim3 grid(MB, 1);
        gemm_mfma_kernel<false, true><<<grid, 256, 0, stream>>>(h2, mean, wt3, b3, out, DHID, DOUT);
    }
}

// Round 4
// 243.929 us; speedup vs baseline: 23.5279x; 1.5073x over previous
//
#include <hip/hip_runtime.h>

#define NNODES 40000
#define NEDGES 640000
#define DIN 128
#define DHID 256
#define DOUT 47
#define NCNT 40960
#define NPART (NCNT / 256)

typedef __attribute__((ext_vector_type(8))) short short8;
typedef __attribute__((ext_vector_type(4))) float f32x4;

__device__ inline float bf2f(unsigned short u) {
    union { unsigned int i; float f; } c; c.i = ((unsigned int)u) << 16; return c.f;
}
__device__ inline unsigned short f2bf(float f) {
    union { float f; unsigned int i; } c; c.f = f;
    unsigned int x = c.i;
    x += 0x7fff + ((x >> 16) & 1);  // RNE
    return (unsigned short)(x >> 16);
}

// ---------------- CSR build ----------------
__global__ void hist_kernel(const int* __restrict__ dst, int* __restrict__ cnt) {
    int t = blockIdx.x * blockDim.x + threadIdx.x;
    if (t < NEDGES) atomicAdd(&cnt[dst[t]], 1);
}

__global__ void part_kernel(const int* __restrict__ cnt, int* __restrict__ part) {
    int b = blockIdx.x, t = threadIdx.x;
    int v = cnt[b * 256 + t];
#pragma unroll
    for (int off = 32; off > 0; off >>= 1) v += __shfl_down(v, off);
    __shared__ int ws[4];
    if ((t & 63) == 0) ws[t >> 6] = v;
    __syncthreads();
    if (t == 0) part[b] = ws[0] + ws[1] + ws[2] + ws[3];
}

__global__ void scanpart_kernel(const int* __restrict__ part, int* __restrict__ partoff) {
    __shared__ int sh[256];
    int t = threadIdx.x;
    int v = (t < NPART) ? part[t] : 0;
    sh[t] = v;
    __syncthreads();
    for (int off = 1; off < 256; off <<= 1) {
        int add = (t >= off) ? sh[t - off] : 0;
        __syncthreads();
        sh[t] += add;
        __syncthreads();
    }
    if (t < NPART) partoff[t] = sh[t] - v;
}

__global__ void writeptr_kernel(const int* __restrict__ cnt, const int* __restrict__ partoff,
                                int* __restrict__ rowptr) {
    __shared__ int sh[256];
    int b = blockIdx.x, t = threadIdx.x;
    int idx = b * 256 + t;
    int v = cnt[idx];
    sh[t] = v;
    __syncthreads();
    for (int off = 1; off < 256; off <<= 1) {
        int add = (t >= off) ? sh[t - off] : 0;
        __syncthreads();
        sh[t] += add;
        __syncthreads();
    }
    rowptr[idx] = partoff[b] + sh[t] - v;
}

__global__ void fill_kernel(const int* __restrict__ src, const int* __restrict__ dst,
                            const int* __restrict__ rowptr, int* __restrict__ fill,
                            int* __restrict__ eidx) {
    int e = blockIdx.x * blockDim.x + threadIdx.x;
    if (e < NEDGES) {
        int d = dst[e];
        int pos = rowptr[d] + atomicAdd(&fill[d], 1);
        eidx[pos] = src[e];
    }
}

// ---------------- conversions ----------------
__global__ void f32_to_bf16_kernel(const float* __restrict__ in, unsigned short* __restrict__ out, int n) {
    int t = blockIdx.x * blockDim.x + threadIdx.x;
    if (t < n) out[t] = f2bf(in[t]);
}

__global__ void conv_wt_kernel(const float* __restrict__ W, unsigned short* __restrict__ Wt, int K, int N) {
    int t = blockIdx.x * blockDim.x + threadIdx.x;
    if (t < K * N) {
        int k = t / N, n = t - k * N;
        Wt[(size_t)n * K + k] = f2bf(W[t]);
    }
}

// W3 [512][47] -> Wt3 [94][256]: row n<47 = W3_top col n; row n>=47 = W3_bot col n-47
__global__ void conv_wt3_kernel(const float* __restrict__ W3, unsigned short* __restrict__ Wt) {
    int t = blockIdx.x * blockDim.x + threadIdx.x;
    if (t < 94 * 256) {
        int n = t >> 8, k = t & 255;
        float v = (n < 47) ? W3[(size_t)k * DOUT + n]
                           : W3[(size_t)(k + DHID) * DOUT + (n - 47)];
        Wt[t] = f2bf(v);
    }
}

// ---------------- mean aggregation (bf16, wave/node, 4x ILP) ----------------
template <int D>
__global__ void agg_bf16_kernel(const unsigned short* __restrict__ h,
                                const int* __restrict__ rowptr,
                                const int* __restrict__ eidx,
                                unsigned short* __restrict__ mean) {
    constexpr int VPL = D / 64;
    const int node = blockIdx.x * (blockDim.x >> 6) + (threadIdx.x >> 6);
    if (node >= NNODES) return;
    const int lane = threadIdx.x & 63;
    const int beg = rowptr[node], end = rowptr[node + 1];
    const unsigned short* hp = h + lane * VPL;

    float acc[VPL];
#pragma unroll
    for (int i = 0; i < VPL; ++i) acc[i] = 0.0f;

    for (int base = beg; base < end; base += 64) {
        int n = min(64, end - base);
        int myidx = (base + lane < end) ? eidx[base + lane] : 0;
        int j = 0;
        for (; j + 4 <= n; j += 4) {
            int s0 = __shfl(myidx, j);
            int s1 = __shfl(myidx, j + 1);
            int s2 = __shfl(myidx, j + 2);
            int s3 = __shfl(myidx, j + 3);
            if constexpr (VPL == 4) {
                ushort4 v0 = *(const ushort4*)(hp + (size_t)s0 * D);
                ushort4 v1 = *(const ushort4*)(hp + (size_t)s1 * D);
                ushort4 v2 = *(const ushort4*)(hp + (size_t)s2 * D);
                ushort4 v3 = *(const ushort4*)(hp + (size_t)s3 * D);
                acc[0] += (bf2f(v0.x) + bf2f(v1.x)) + (bf2f(v2.x) + bf2f(v3.x));
                acc[1] += (bf2f(v0.y) + bf2f(v1.y)) + (bf2f(v2.y) + bf2f(v3.y));
                acc[2] += (bf2f(v0.z) + bf2f(v1.z)) + (bf2f(v2.z) + bf2f(v3.z));
                acc[3] += (bf2f(v0.w) + bf2f(v1.w)) + (bf2f(v2.w) + bf2f(v3.w));
            } else {
                ushort2 v0 = *(const ushort2*)(hp + (size_t)s0 * D);
                ushort2 v1 = *(const ushort2*)(hp + (size_t)s1 * D);
                ushort2 v2 = *(const ushort2*)(hp + (size_t)s2 * D);
                ushort2 v3 = *(const ushort2*)(hp + (size_t)s3 * D);
                acc[0] += (bf2f(v0.x) + bf2f(v1.x)) + (bf2f(v2.x) + bf2f(v3.x));
                acc[1] += (bf2f(v0.y) + bf2f(v1.y)) + (bf2f(v2.y) + bf2f(v3.y));
            }
        }
        for (; j < n; ++j) {
            int s = __shfl(myidx, j);
            if constexpr (VPL == 4) {
                ushort4 v = *(const ushort4*)(hp + (size_t)s * D);
                acc[0] += bf2f(v.x); acc[1] += bf2f(v.y);
                acc[2] += bf2f(v.z); acc[3] += bf2f(v.w);
            } else {
                ushort2 v = *(const ushort2*)(hp + (size_t)s * D);
                acc[0] += bf2f(v.x); acc[1] += bf2f(v.y);
            }
        }
    }
    float inv = (end > beg) ? 1.0f / (float)(end - beg) : 0.0f;
    unsigned short* o = mean + (size_t)node * D + lane * VPL;
    if constexpr (VPL == 4) {
        ushort4 r;
        r.x = f2bf(acc[0] * inv); r.y = f2bf(acc[1] * inv);
        r.z = f2bf(acc[2] * inv); r.w = f2bf(acc[3] * inv);
        *(ushort4*)o = r;
    } else {
        ushort2 r;
        r.x = f2bf(acc[0] * inv); r.y = f2bf(acc[1] * inv);
        *(ushort2*)o = r;
    }
}

// ---------------- layer-3 P aggregation ----------------
__global__ void agg_p_kernel(const unsigned short* __restrict__ P,
                             const int* __restrict__ rowptr,
                             const int* __restrict__ eidx,
                             float* __restrict__ out) {
    const int node = blockIdx.x * (blockDim.x >> 6) + (threadIdx.x >> 6);
    if (node >= NNODES) return;
    const int lane = threadIdx.x & 63;
    const int beg = rowptr[node], end = rowptr[node + 1];
    const bool active = lane < 48;
    const int lc = active ? lane : 0;

    float acc = 0.0f;
    for (int base = beg; base < end; base += 64) {
        int n = min(64, end - base);
        int myidx = (base + lane < end) ? eidx[base + lane] : 0;
        int j = 0;
        for (; j + 4 <= n; j += 4) {
            int s0 = __shfl(myidx, j);
            int s1 = __shfl(myidx, j + 1);
            int s2 = __shfl(myidx, j + 2);
            int s3 = __shfl(myidx, j + 3);
            if (active) {
                float a = bf2f(P[(size_t)s0 * 48 + lc]) + bf2f(P[(size_t)s1 * 48 + lc]);
                float b = bf2f(P[(size_t)s2 * 48 + lc]) + bf2f(P[(size_t)s3 * 48 + lc]);
                acc += a + b;
            }
        }
        for (; j < n; ++j) {
            int s = __shfl(myidx, j);
            if (active) acc += bf2f(P[(size_t)s * 48 + lc]);
        }
    }
    if (lane < 47 && end > beg) {
        out[(size_t)node * DOUT + lane] += acc / (float)(end - beg);
    }
}

// ---------------- bf16 MFMA GEMM ----------------
// MODE 0: A = [H | Mn] virtual concat, K = 2*d, out bf16 [M][N] with relu+bias.
// MODE 2: A = H with row stride K (=2*d passed via d=K/2), dual out:
//         col<47 -> f32 out [M][47] + bias;  col in [47,94) -> Pout bf16 [M][48].
template <int MODE>
__launch_bounds__(256, 2)
__global__ void gemm_mfma_kernel(const unsigned short* __restrict__ H,
                                 const unsigned short* __restrict__ Mn,
                                 const unsigned short* __restrict__ Wt,
                                 const float* __restrict__ bias,
                                 void* __restrict__ outp,
                                 unsigned short* __restrict__ Pout,
                                 int d, int N) {
    const int K = 2 * d;
    __shared__ uint4 AsB[128 * 4];
    __shared__ uint4 BsB[128 * 4];

    const int tid = threadIdx.x;
    const int lane = tid & 63;
    const int wid = tid >> 6;
    const int wr = wid >> 1, wc = wid & 1;
    const int row0 = blockIdx.x * 128;
    const int col0 = blockIdx.y * 128;

    const int sr = tid >> 1;
    const int sh = tid & 1;
    const int gar = min(row0 + sr, NNODES - 1);
    const int gbr = min(col0 + sr, N - 1);
    const int ssw = (sr >> 1) & 3;

    f32x4 acc[4][4];
#pragma unroll
    for (int m = 0; m < 4; ++m)
#pragma unroll
        for (int n = 0; n < 4; ++n) {
            f32x4 z = {0.0f, 0.0f, 0.0f, 0.0f};
            acc[m][n] = z;
        }

    for (int k0 = 0; k0 < K; k0 += 32) {
        {
            int kb = k0 + sh * 16;
            const unsigned short* p;
            if (MODE == 2) {
                p = H + (size_t)gar * K + kb;  // plain A, row stride K
            } else {
                p = (kb < d) ? (H + (size_t)gar * d + kb)
                             : (Mn + (size_t)gar * d + (kb - d));
            }
            uint4 v0 = *(const uint4*)p;
            uint4 v1 = *(const uint4*)(p + 8);
            AsB[sr * 4 + ((2 * sh) ^ ssw)]     = v0;
            AsB[sr * 4 + ((2 * sh + 1) ^ ssw)] = v1;
        }
        {
            const unsigned short* p = Wt + (size_t)gbr * K + k0 + sh * 16;
            uint4 v0 = *(const uint4*)p;
            uint4 v1 = *(const uint4*)(p + 8);
            BsB[sr * 4 + ((2 * sh) ^ ssw)]     = v0;
            BsB[sr * 4 + ((2 * sh + 1) ^ ssw)] = v1;
        }
        __syncthreads();

        short8 af[4], bfr[4];
        const int fr = lane & 15;
        const int slot = lane >> 4;
#pragma unroll
        for (int m = 0; m < 4; ++m) {
            int r = wr * 64 + m * 16 + fr;
            union { uint4 u; short8 s; } c;
            c.u = AsB[r * 4 + (slot ^ ((r >> 1) & 3))];
            af[m] = c.s;
        }
#pragma unroll
        for (int n = 0; n < 4; ++n) {
            int r = wc * 64 + n * 16 + fr;
            union { uint4 u; short8 s; } c;
            c.u = BsB[r * 4 + (slot ^ ((r >> 1) & 3))];
            bfr[n] = c.s;
        }
#pragma unroll
        for (int m = 0; m < 4; ++m)
#pragma unroll
            for (int n = 0; n < 4; ++n)
                acc[m][n] = __builtin_amdgcn_mfma_f32_16x16x32_bf16(af[m], bfr[n], acc[m][n], 0, 0, 0);
        __syncthreads();
    }

#pragma unroll
    for (int m = 0; m < 4; ++m) {
#pragma unroll
        for (int n = 0; n < 4; ++n) {
            int col = col0 + wc * 64 + n * 16 + (lane & 15);
            if (col >= N) continue;
            float bv = (MODE == 0) ? bias[col] : ((col < 47) ? bias[col] : 0.0f);
#pragma unroll
            for (int q = 0; q < 4; ++q) {
                int row = row0 + wr * 64 + m * 16 + (lane >> 4) * 4 + q;
                if (row < NNODES) {
                    float v = acc[m][n][q] + bv;
                    if (MODE == 0) {
                        v = fmaxf(v, 0.0f);
                        ((unsigned short*)outp)[(size_t)row * N + col] = f2bf(v);
                    } else {
                        if (col < 47) ((float*)outp)[(size_t)row * DOUT + col] = v;
                        else Pout[(size_t)row * 48 + (col - 47)] = f2bf(v);
                    }
                }
            }
        }
    }
}

extern "C" void kernel_launch(void* const* d_in, const int* in_sizes, int n_in,
                              void* d_out, int out_size, void* d_ws, size_t ws_size,
                              hipStream_t stream) {
    const float* x  = (const float*)d_in[0];
    const float* W1 = (const float*)d_in[1];
    const float* b1 = (const float*)d_in[2];
    const float* W2 = (const float*)d_in[3];
    const float* b2 = (const float*)d_in[4];
    const float* W3 = (const float*)d_in[5];
    const float* b3 = (const float*)d_in[6];
    const int* src  = (const int*)d_in[7];
    const int* dst  = (const int*)d_in[8];
    float* out = (float*)d_out;

    int* rowptr  = (int*)d_ws;
    int* eidx    = rowptr + NCNT;
    int* cnt     = eidx + NEDGES;
    int* fill    = cnt + NCNT;
    int* part    = fill + NCNT;
    int* partoff = part + 256;
    unsigned short* xbf  = (unsigned short*)(partoff + 256);
    unsigned short* h1   = xbf + (size_t)NNODES * DIN;
    unsigned short* h2   = h1 + (size_t)NNODES * DHID;
    unsigned short* mean = h2 + (size_t)NNODES * DHID;
    unsigned short* wt1  = mean + (size_t)NNODES * DHID;
    unsigned short* wt2  = wt1 + 2 * DIN * DHID;
    unsigned short* wt3  = wt2 + 2 * DHID * DHID;
    unsigned short* P    = mean;  // layer-3 reuse (mean dead by then)

    // ---- CSR build ----
    hipMemsetAsync(cnt, 0, 2 * NCNT * sizeof(int), stream);
    hist_kernel<<<(NEDGES + 255) / 256, 256, 0, stream>>>(dst, cnt);
    part_kernel<<<NPART, 256, 0, stream>>>(cnt, part);
    scanpart_kernel<<<1, 256, 0, stream>>>(part, partoff);
    writeptr_kernel<<<NPART, 256, 0, stream>>>(cnt, partoff, rowptr);
    fill_kernel<<<(NEDGES + 255) / 256, 256, 0, stream>>>(src, dst, rowptr, fill, eidx);

    // ---- conversions ----
    f32_to_bf16_kernel<<<(NNODES * DIN + 255) / 256, 256, 0, stream>>>(x, xbf, NNODES * DIN);
    conv_wt_kernel<<<(2 * DIN * DHID + 255) / 256, 256, 0, stream>>>(W1, wt1, 2 * DIN, DHID);
    conv_wt_kernel<<<(2 * DHID * DHID + 255) / 256, 256, 0, stream>>>(W2, wt2, 2 * DHID, DHID);
    conv_wt3_kernel<<<(94 * 256 + 255) / 256, 256, 0, stream>>>(W3, wt3);

    const int MB = (NNODES + 127) / 128;  // 313

    // ---- layer 1
    agg_bf16_kernel<DIN><<<NNODES / 4, 256, 0, stream>>>(xbf, rowptr, eidx, mean);
    {
        dim3 grid(MB, 2);
        gemm_mfma_kernel<0><<<grid, 256, 0, stream>>>(xbf, mean, wt1, b1, h1, nullptr, DIN, DHID);
    }

    // ---- layer 2
    agg_bf16_kernel<DHID><<<NNODES / 4, 256, 0, stream>>>(h1, rowptr, eidx, mean);
    {
        dim3 grid(MB, 2);
        gemm_mfma_kernel<0><<<grid, 256, 0, stream>>>(h1, mean, wt2, b2, h2, nullptr, DHID, DHID);
    }

    // ---- layer 3: dual GEMM (K=256 via d=128; A row stride = K), then P-aggregate
    {
        dim3 grid(MB, 1);
        gemm_mfma_kernel<2><<<grid, 256, 0, stream>>>(h2, h2, wt3, b3, out, P, DHID / 2, 94);
    }
    agg_p_kernel<<<NNODES / 4, 256, 0, stream>>>(P, rowptr, eidx, out);
}